// Round 1
// baseline (193.397 us; speedup 1.0000x reference)
//
#include <hip/hip_runtime.h>

#define T 8
#define VTH 1.0f
#define BN_EPS 1e-5f

// Kernel 1: conv3x3(pad=1) + BN(eval) + IF(8 steps, hard reset) + maxpool2x2(OR)
// One block per (b,c). 196 active threads, one per pooled output position.
// Output: f[b][c][196] = 8-bit spike mask over timesteps.
__global__ __launch_bounds__(256) void k_conv_if_pool(
    const float* __restrict__ x,       // [128,1,28,28]
    const float* __restrict__ conv_w,  // [128,1,3,3]
    const float* __restrict__ gamma,   // [128]
    const float* __restrict__ beta,    // [128]
    const float* __restrict__ mean,    // [128]
    const float* __restrict__ var,     // [128]
    unsigned char* __restrict__ f)     // [128,128,196] bitmasks
{
    __shared__ float xs[30 * 30];      // zero-padded input image
    const int blk = blockIdx.x;        // b*128 + c
    const int b = blk >> 7;
    const int c = blk & 127;
    const int tid = threadIdx.x;

    for (int i = tid; i < 900; i += 256) xs[i] = 0.0f;
    __syncthreads();
    const float* xb = x + b * 784;
    for (int i = tid; i < 784; i += 256) {
        int h = i / 28, w = i - h * 28;
        xs[(h + 1) * 30 + (w + 1)] = xb[i];
    }
    __syncthreads();

    if (tid >= 196) return;
    const int ph = tid / 14, pw = tid - ph * 14;

    float wv[9];
    const float* wc = conv_w + c * 9;
    #pragma unroll
    for (int i = 0; i < 9; i++) wv[i] = wc[i];
    const float sc = gamma[c] * rsqrtf(var[c] + BN_EPS);
    const float sh = beta[c] - mean[c] * sc;   // pre = y*sc + sh

    unsigned int bits = 0;
    #pragma unroll
    for (int dy = 0; dy < 2; dy++) {
        #pragma unroll
        for (int dx = 0; dx < 2; dx++) {
            const int h = 2 * ph + dy, w = 2 * pw + dx;
            float y = 0.0f;
            #pragma unroll
            for (int kh = 0; kh < 3; kh++)
                #pragma unroll
                for (int kw = 0; kw < 3; kw++)
                    y += xs[(h + kh) * 30 + (w + kw)] * wv[kh * 3 + kw];
            const float p = y * sc + sh;
            // IF dynamics: v += p; spike if v-VTH >= 0; hard reset to 0.
            float v = 0.0f;
            #pragma unroll
            for (int t = 0; t < T; t++) {
                v += p;
                if (v - VTH >= 0.0f) { bits |= (1u << t); v = 0.0f; }
            }
        }
    }
    f[blk * 196 + tid] = (unsigned char)bits;   // maxpool of binaries == OR of masks
}

// Kernel 2: per-timestep FC accumulation + IF on the 10 outputs + rate.
// One block per batch element. acc[t][o] = sum_k bit(f[b][k],t) * fc_w[o][k].
__global__ __launch_bounds__(256) void k_fc_if(
    const unsigned char* __restrict__ f,   // [128, 25088]
    const float* __restrict__ fc_w,        // [10, 25088]
    float* __restrict__ out)               // [128, 10]
{
    const int b = blockIdx.x;
    const int tid = threadIdx.x;
    const int lane = tid & 63;
    const int wave = tid >> 6;

    float acc[T * 10];
    #pragma unroll
    for (int i = 0; i < T * 10; i++) acc[i] = 0.0f;

    const unsigned char* fb = f + b * 25088;
    for (int k = tid; k < 25088; k += 256) {
        const unsigned int m = fb[k];
        if (m == 0) continue;
        #pragma unroll
        for (int o = 0; o < 10; o++) {
            const float w = fc_w[o * 25088 + k];
            #pragma unroll
            for (int t = 0; t < T; t++) {
                if (m & (1u << t)) acc[t * 10 + o] += w;
            }
        }
    }

    __shared__ float red[4][T * 10];
    #pragma unroll
    for (int i = 0; i < T * 10; i++) {
        float v = acc[i];
        #pragma unroll
        for (int off = 32; off > 0; off >>= 1)
            v += __shfl_down(v, off, 64);
        if (lane == 0) red[wave][i] = v;
    }
    __syncthreads();

    if (tid < 10) {
        float v2 = 0.0f, cnt = 0.0f;
        #pragma unroll
        for (int t = 0; t < T; t++) {
            const float a = red[0][t * 10 + tid] + red[1][t * 10 + tid] +
                            red[2][t * 10 + tid] + red[3][t * 10 + tid];
            v2 += a;
            if (v2 - VTH >= 0.0f) { cnt += 1.0f; v2 = 0.0f; }
        }
        out[b * 10 + tid] = cnt * (1.0f / (float)T);
    }
}

extern "C" void kernel_launch(void* const* d_in, const int* in_sizes, int n_in,
                              void* d_out, int out_size, void* d_ws, size_t ws_size,
                              hipStream_t stream) {
    const float* x      = (const float*)d_in[0];  // [128,1,28,28]
    const float* conv_w = (const float*)d_in[1];  // [128,1,3,3]
    const float* gamma  = (const float*)d_in[2];
    const float* beta   = (const float*)d_in[3];
    const float* mean   = (const float*)d_in[4];
    const float* var    = (const float*)d_in[5];
    const float* fc_w   = (const float*)d_in[6];  // [10, 25088]
    float* out = (float*)d_out;                    // [128,10]

    unsigned char* f = (unsigned char*)d_ws;       // 128*25088 = 3.2 MB bitmasks

    k_conv_if_pool<<<128 * 128, 256, 0, stream>>>(x, conv_w, gamma, beta, mean, var, f);
    k_fc_if<<<128, 256, 0, stream>>>(f, fc_w, out);
}

// Round 2
// 119.858 us; speedup vs baseline: 1.6136x; 1.6136x over previous
//
#include <hip/hip_runtime.h>

#define T 8
#define VTH 1.0f
#define BN_EPS 1e-5f
#define CG 16          // channels per K1 block
#define NG (128 / CG)  // channel groups

// Kernel 1: conv3x3(pad=1) + BN(eval) + IF(8 steps, hard reset) + maxpool2x2(OR)
// One block per (b, channel-group). 196 active threads, one per pooled position.
// Each thread caches its 4x4 input patch in registers, loops CG channels.
__global__ __launch_bounds__(256) void k_conv_if_pool(
    const float* __restrict__ x,       // [128,1,28,28]
    const float* __restrict__ conv_w,  // [128,1,3,3]
    const float* __restrict__ gamma,   // [128]
    const float* __restrict__ beta,    // [128]
    const float* __restrict__ mean,    // [128]
    const float* __restrict__ var,     // [128]
    unsigned char* __restrict__ f)     // [128,128,196] bitmasks
{
    __shared__ float xs[30 * 30];      // zero-padded input image
    const int blk = blockIdx.x;        // b*NG + g
    const int b = blk / NG;
    const int g = blk - b * NG;
    const int tid = threadIdx.x;

    for (int i = tid; i < 900; i += 256) xs[i] = 0.0f;
    __syncthreads();
    const float* xb = x + b * 784;
    for (int i = tid; i < 784; i += 256) {
        int h = i / 28, w = i - h * 28;
        xs[(h + 1) * 30 + (w + 1)] = xb[i];
    }
    __syncthreads();

    if (tid >= 196) return;
    const int ph = tid / 14, pw = tid - ph * 14;

    // 4x4 input patch for this pooled position (covers both conv cells + halo)
    float patch[16];
    const int base = (2 * ph) * 30 + 2 * pw;
    #pragma unroll
    for (int r = 0; r < 4; r++)
        #pragma unroll
        for (int cc = 0; cc < 4; cc++)
            patch[r * 4 + cc] = xs[base + r * 30 + cc];

    for (int ci = 0; ci < CG; ci++) {
        const int c = g * CG + ci;
        const float* wc = conv_w + c * 9;   // uniform across threads -> s_load
        float wv[9];
        #pragma unroll
        for (int i = 0; i < 9; i++) wv[i] = wc[i];
        const float sc = gamma[c] * rsqrtf(var[c] + BN_EPS);
        const float sh = beta[c] - mean[c] * sc;   // pre = y*sc + sh

        unsigned int bits = 0;
        #pragma unroll
        for (int dy = 0; dy < 2; dy++) {
            #pragma unroll
            for (int dx = 0; dx < 2; dx++) {
                float y = 0.0f;
                #pragma unroll
                for (int kh = 0; kh < 3; kh++)
                    #pragma unroll
                    for (int kw = 0; kw < 3; kw++)
                        y += patch[(dy + kh) * 4 + (dx + kw)] * wv[kh * 3 + kw];
                const float p = y * sc + sh;
                float v = 0.0f;
                #pragma unroll
                for (int t = 0; t < T; t++) {
                    v += p;
                    if (v - VTH >= 0.0f) { bits |= (1u << t); v = 0.0f; }
                }
            }
        }
        f[(b * 128 + c) * 196 + tid] = (unsigned char)bits;  // pool == OR of masks
    }
}

// Kernel 2: one block per (b, o). acc[t] = sum_k bit(f[b][k],t) * fc_w[o][k],
// then IF over the 8 timesteps and write firing rate.
__global__ __launch_bounds__(256) void k_fc_if(
    const unsigned char* __restrict__ f,   // [128, 25088]
    const float* __restrict__ fc_w,        // [10, 25088]
    float* __restrict__ out)               // [128, 10]
{
    const int blk = blockIdx.x;            // b*10 + o
    const int b = blk / 10;
    const int o = blk - b * 10;
    const int tid = threadIdx.x;
    const int lane = tid & 63;
    const int wave = tid >> 6;

    const unsigned int* fm = (const unsigned int*)(f + b * 25088);
    const float4* fw = (const float4*)(fc_w + o * 25088);

    float acc[T];
    #pragma unroll
    for (int t = 0; t < T; t++) acc[t] = 0.0f;

    for (int i = tid; i < 25088 / 4; i += 256) {
        const unsigned int m4 = fm[i];
        const float4 w = fw[i];
        const float wj[4] = {w.x, w.y, w.z, w.w};
        #pragma unroll
        for (int j = 0; j < 4; j++) {
            const unsigned int m = (m4 >> (8 * j)) & 0xffu;
            #pragma unroll
            for (int t = 0; t < T; t++) {
                if (m & (1u << t)) acc[t] += wj[j];
            }
        }
    }

    __shared__ float red[4][T];
    #pragma unroll
    for (int t = 0; t < T; t++) {
        float v = acc[t];
        #pragma unroll
        for (int off = 32; off > 0; off >>= 1)
            v += __shfl_down(v, off, 64);
        if (lane == 0) red[wave][t] = v;
    }
    __syncthreads();

    if (tid == 0) {
        float v2 = 0.0f, cnt = 0.0f;
        #pragma unroll
        for (int t = 0; t < T; t++) {
            const float a = red[0][t] + red[1][t] + red[2][t] + red[3][t];
            v2 += a;
            if (v2 - VTH >= 0.0f) { cnt += 1.0f; v2 = 0.0f; }
        }
        out[b * 10 + o] = cnt * (1.0f / (float)T);
    }
}

extern "C" void kernel_launch(void* const* d_in, const int* in_sizes, int n_in,
                              void* d_out, int out_size, void* d_ws, size_t ws_size,
                              hipStream_t stream) {
    const float* x      = (const float*)d_in[0];  // [128,1,28,28]
    const float* conv_w = (const float*)d_in[1];  // [128,1,3,3]
    const float* gamma  = (const float*)d_in[2];
    const float* beta   = (const float*)d_in[3];
    const float* mean   = (const float*)d_in[4];
    const float* var    = (const float*)d_in[5];
    const float* fc_w   = (const float*)d_in[6];  // [10, 25088]
    float* out = (float*)d_out;                    // [128,10]

    unsigned char* f = (unsigned char*)d_ws;       // 128*25088 = 3.2 MB bitmasks

    k_conv_if_pool<<<128 * NG, 256, 0, stream>>>(x, conv_w, gamma, beta, mean, var, f);
    k_fc_if<<<128 * 10, 256, 0, stream>>>(f, fc_w, out);
}

// Round 3
// 116.660 us; speedup vs baseline: 1.6578x; 1.0274x over previous
//
#include <hip/hip_runtime.h>

#define T 8
#define VTH 1.0f
#define BN_EPS 1e-5f
#define CG 8           // channels per K1 block (fully unrolled -> s_loads hoisted)
#define NG (128 / CG)  // channel groups

// Kernel 1: conv3x3(pad=1) + BN(eval) + IF(8 steps, hard reset) + maxpool2x2(OR)
// One block per (b, channel-group). 196 active threads, one per pooled position.
__global__ __launch_bounds__(256) void k_conv_if_pool(
    const float* __restrict__ x,       // [128,1,28,28]
    const float* __restrict__ conv_w,  // [128,1,3,3]
    const float* __restrict__ gamma,   // [128]
    const float* __restrict__ beta,    // [128]
    const float* __restrict__ mean,    // [128]
    const float* __restrict__ var,     // [128]
    unsigned char* __restrict__ f)     // [128,128,196] bitmasks
{
    __shared__ float xs[30 * 30];      // zero-padded input image
    const int blk = blockIdx.x;        // b*NG + g
    const int b = blk / NG;
    const int g = blk - b * NG;
    const int tid = threadIdx.x;

    for (int i = tid; i < 900; i += 256) xs[i] = 0.0f;
    __syncthreads();
    const float* xb = x + b * 784;
    for (int i = tid; i < 784; i += 256) {
        int h = i / 28, w = i - h * 28;
        xs[(h + 1) * 30 + (w + 1)] = xb[i];
    }
    __syncthreads();

    if (tid >= 196) return;
    const int ph = tid / 14, pw = tid - ph * 14;

    // 4x4 input patch for this pooled position (both conv cells + halo)
    float patch[16];
    const int base = (2 * ph) * 30 + 2 * pw;
    #pragma unroll
    for (int r = 0; r < 4; r++)
        #pragma unroll
        for (int cc = 0; cc < 4; cc++)
            patch[r * 4 + cc] = xs[base + r * 30 + cc];

    #pragma unroll
    for (int ci = 0; ci < CG; ci++) {
        const int c = g * CG + ci;
        const float* wc = conv_w + c * 9;   // uniform -> scalar loads, hoisted
        float wv[9];
        #pragma unroll
        for (int i = 0; i < 9; i++) wv[i] = wc[i];
        const float sc = gamma[c] * rsqrtf(var[c] + BN_EPS);
        const float sh = beta[c] - mean[c] * sc;   // pre = y*sc + sh

        unsigned int bits = 0;
        #pragma unroll
        for (int dy = 0; dy < 2; dy++) {
            #pragma unroll
            for (int dx = 0; dx < 2; dx++) {
                float y = 0.0f;
                #pragma unroll
                for (int kh = 0; kh < 3; kh++)
                    #pragma unroll
                    for (int kw = 0; kw < 3; kw++)
                        y += patch[(dy + kh) * 4 + (dx + kw)] * wv[kh * 3 + kw];
                const float p = y * sc + sh;
                float v = 0.0f;
                #pragma unroll
                for (int t = 0; t < T; t++) {
                    v += p;
                    if (v - VTH >= 0.0f) { bits |= (1u << t); v = 0.0f; }
                }
            }
        }
        f[(b * 128 + c) * 196 + tid] = (unsigned char)bits;  // pool == OR of masks
    }
}

// Kernel 2: one block per (b, output-group of 5). Bit decode shared across the
// 5 outputs; 1 fma per (t,o,k). Then IF over 8 timesteps, write firing rate.
__global__ __launch_bounds__(512) void k_fc_if(
    const unsigned char* __restrict__ f,   // [128, 25088]
    const float* __restrict__ fc_w,        // [10, 25088]
    float* __restrict__ out)               // [128, 10]
{
    const int blk = blockIdx.x;            // b*2 + og
    const int b = blk >> 1;
    const int og = blk & 1;                // outputs og*5 .. og*5+4
    const int tid = threadIdx.x;
    const int lane = tid & 63;
    const int wave = tid >> 6;

    const unsigned int* fm = (const unsigned int*)(f + b * 25088);
    const float4* fw0 = (const float4*)(fc_w + (og * 5 + 0) * 25088);
    const float4* fw1 = (const float4*)(fc_w + (og * 5 + 1) * 25088);
    const float4* fw2 = (const float4*)(fc_w + (og * 5 + 2) * 25088);
    const float4* fw3 = (const float4*)(fc_w + (og * 5 + 3) * 25088);
    const float4* fw4 = (const float4*)(fc_w + (og * 5 + 4) * 25088);

    float acc[T][5];
    #pragma unroll
    for (int t = 0; t < T; t++)
        #pragma unroll
        for (int o = 0; o < 5; o++) acc[t][o] = 0.0f;

    for (int i = tid; i < 25088 / 4; i += 512) {
        const unsigned int m4 = fm[i];
        float4 w[5] = {fw0[i], fw1[i], fw2[i], fw3[i], fw4[i]};
        #pragma unroll
        for (int j = 0; j < 4; j++) {
            const float wj[5] = {((const float*)&w[0])[j], ((const float*)&w[1])[j],
                                 ((const float*)&w[2])[j], ((const float*)&w[3])[j],
                                 ((const float*)&w[4])[j]};
            #pragma unroll
            for (int t = 0; t < T; t++) {
                const float bit = (float)((m4 >> (8 * j + t)) & 1u);  // bfe+cvt
                #pragma unroll
                for (int o = 0; o < 5; o++)
                    acc[t][o] = fmaf(bit, wj[o], acc[t][o]);  // exact: +w or +0
            }
        }
    }

    __shared__ float red[8][T * 5];
    #pragma unroll
    for (int t = 0; t < T; t++)
        #pragma unroll
        for (int o = 0; o < 5; o++) {
            float v = acc[t][o];
            #pragma unroll
            for (int off = 32; off > 0; off >>= 1)
                v += __shfl_down(v, off, 64);
            if (lane == 0) red[wave][t * 5 + o] = v;
        }
    __syncthreads();

    __shared__ float tot[T * 5];
    if (tid < T * 5) {
        float s = 0.0f;
        #pragma unroll
        for (int wv = 0; wv < 8; wv++) s += red[wv][tid];
        tot[tid] = s;
    }
    __syncthreads();

    if (tid < 5) {
        float v2 = 0.0f, cnt = 0.0f;
        #pragma unroll
        for (int t = 0; t < T; t++) {
            v2 += tot[t * 5 + tid];
            if (v2 - VTH >= 0.0f) { cnt += 1.0f; v2 = 0.0f; }
        }
        out[b * 10 + og * 5 + tid] = cnt * (1.0f / (float)T);
    }
}

extern "C" void kernel_launch(void* const* d_in, const int* in_sizes, int n_in,
                              void* d_out, int out_size, void* d_ws, size_t ws_size,
                              hipStream_t stream) {
    const float* x      = (const float*)d_in[0];  // [128,1,28,28]
    const float* conv_w = (const float*)d_in[1];  // [128,1,3,3]
    const float* gamma  = (const float*)d_in[2];
    const float* beta   = (const float*)d_in[3];
    const float* mean   = (const float*)d_in[4];
    const float* var    = (const float*)d_in[5];
    const float* fc_w   = (const float*)d_in[6];  // [10, 25088]
    float* out = (float*)d_out;                    // [128,10]

    unsigned char* f = (unsigned char*)d_ws;       // 128*25088 = 3.2 MB bitmasks

    k_conv_if_pool<<<128 * NG, 256, 0, stream>>>(x, conv_w, gamma, beta, mean, var, f);
    k_fc_if<<<128 * 2, 512, 0, stream>>>(f, fc_w, out);
}